// Round 4
// baseline (573.412 us; speedup 1.0000x reference)
//
#include <hip/hip_runtime.h>

// VQ nearest-codeword, 2-tier:
//  T1: fp16 single-pass MFMA GEMM (x,E pre-packed fp16), fused per-row top-2.
//      rows with top-2 gap < TAU1 -> list1.  (round-2-proven structure)
//  T2: exact fp64 re-argmin of list1 rows (batched, LDS-staged E tiles).
// xpack placement: d_ws when large enough (no aliasing), else d_out
// (round-2-proven: each block reads only its own rows, writes them at end).

typedef float f32x4 __attribute__((ext_vector_type(4)));
typedef _Float16 f16x8 __attribute__((ext_vector_type(8)));

#define TAU1 0.15f
#define LIST_CAP 65536u

__device__ __forceinline__ unsigned short f16b(float f) {
  _Float16 h = (_Float16)f;
  return __builtin_bit_cast(unsigned short, h);
}

__device__ __forceinline__ void gl16(char* lds, const char* g) {
  __builtin_amdgcn_global_load_lds(
      (const __attribute__((address_space(1))) void*)g,
      (__attribute__((address_space(3))) void*)lds, 16, 0, 0);
}

// ---- pack x: f32 [32768][256] -> fp16 rows at stride 1024 B ----
__global__ void pack_x(const float* __restrict__ x, char* xp) {
  int gid = blockIdx.x * 256 + threadIdx.x;  // 524288 total
  int row = gid >> 4, seg = gid & 15;
  const float4* xr = (const float4*)(x + (size_t)row * 256 + seg * 16);
  unsigned o[8];
#pragma unroll
  for (int q = 0; q < 4; ++q) {
    float4 f = xr[q];
    o[q * 2]     = (unsigned)f16b(f.x) | ((unsigned)f16b(f.y) << 16);
    o[q * 2 + 1] = (unsigned)f16b(f.z) | ((unsigned)f16b(f.w) << 16);
  }
  uint4* dst = (uint4*)(xp + (size_t)row * 1024 + seg * 32);
  dst[0] = make_uint4(o[0], o[1], o[2], o[3]);
  dst[1] = make_uint4(o[4], o[5], o[6], o[7]);
}

// ---- pack E: fp16 plane (512 B/row) + e2f (f32) + e2d (f64) ----
__global__ void pack_e(const float* __restrict__ E, char* __restrict__ ehi,
                       float* __restrict__ e2f, double* __restrict__ e2d) {
  int tid = threadIdx.x;
  int vl = tid >> 4, seg = tid & 15;
  int v = blockIdx.x * 16 + vl;
  const float4* er = (const float4*)(E + (size_t)v * 256 + seg * 16);
  unsigned oh[8];
  double s = 0.0;
#pragma unroll
  for (int q = 0; q < 4; ++q) {
    float4 f = er[q];
    float vf[4] = {f.x, f.y, f.z, f.w};
    unsigned short hb[4];
#pragma unroll
    for (int e = 0; e < 4; ++e) {
      float fv = vf[e];
      s += (double)fv * (double)fv;
      hb[e] = f16b(fv);
    }
    oh[q * 2]     = (unsigned)hb[0] | ((unsigned)hb[1] << 16);
    oh[q * 2 + 1] = (unsigned)hb[2] | ((unsigned)hb[3] << 16);
  }
  uint4* dh = (uint4*)(ehi + (size_t)v * 512 + seg * 32);
  dh[0] = make_uint4(oh[0], oh[1], oh[2], oh[3]);
  dh[1] = make_uint4(oh[4], oh[5], oh[6], oh[7]);
#pragma unroll
  for (int off = 1; off < 16; off <<= 1) s += __shfl_xor(s, off);
  if (seg == 0) { e2f[v] = (float)s; e2d[v] = s; }
}

// ---- T1 main (round-2-proven): BM=64, chunk=256, BK=32, dbuf LDS ----
__global__ __launch_bounds__(256) void vq_main(
    const char* xpack, const char* __restrict__ epack,
    const float* __restrict__ e2f, const float* __restrict__ E,
    float* out, unsigned* __restrict__ cnt1, unsigned* __restrict__ list1) {
  extern __shared__ char smem[];
  const int tid = threadIdx.x;
  const int w = tid >> 6, lane = tid & 63;
  const int l15 = lane & 15, g = lane >> 4;
  const int rowbase = blockIdx.x * 64;

  // loader geometry (linear LDS dest, inverse-swizzled global source)
  const int rA = w * 16 + (lane >> 2);
  const int swz = (((lane & 3) ^ ((lane >> 2) & 3)) << 4);
  const char* aBase = xpack + (size_t)(rowbase + rA) * 1024 + swz;
  const char* bBase = epack + (size_t)(w * 64 + (lane >> 2)) * 512 + swz;
  const int ldA = w * 1024 + lane * 16;
  const int ldB = w * 4096 + lane * 16;

  // fragment read offsets (XOR-swizzled)
  const int fsw = ((g ^ (l15 & 3)) << 4);
  int aoff[4], boff[4];
#pragma unroll
  for (int mi = 0; mi < 4; ++mi) aoff[mi] = mi * 1024 + l15 * 64 + fsw;
#pragma unroll
  for (int ni = 0; ni < 4; ++ni) boff[ni] = w * 4096 + ni * 1024 + l15 * 64 + fsw;

  f32x4 acc[4][4];
#pragma unroll
  for (int mi = 0; mi < 4; ++mi)
#pragma unroll
    for (int ni = 0; ni < 4; ++ni) acc[mi][ni] = (f32x4){0.f, 0.f, 0.f, 0.f};

  float m1[16], m2[16];
  int i1[16];
#pragma unroll
  for (int s = 0; s < 16; ++s) { m1[s] = 3.4e38f; m2[s] = 3.4e38f; i1[s] = 0; }

#define STAGE(p, coff, koff)                                                \
  do {                                                                      \
    gl16(smem + (p)*4096 + ldA, aBase + (koff));                            \
    _Pragma("unroll") for (int i_ = 0; i_ < 4; ++i_)                        \
        gl16(smem + 8192 + (p)*16384 + ldB + i_ * 1024,                     \
             bBase + i_ * 8192 + (coff) + (koff));                          \
  } while (0)

  STAGE(0, (size_t)0, 0);
  __syncthreads();

#pragma unroll 1
  for (int c = 0; c < 16; ++c) {
    const size_t coff = (size_t)c * 131072;
#pragma unroll
    for (int k = 0; k < 8; ++k) {
      const int p = k & 1;
      if (!(c == 15 && k == 7)) {
        if (k == 7) STAGE(0, coff + 131072, 0);
        else STAGE(p ^ 1, coff, (k + 1) * 64);
      }
      const char* Ar = smem + p * 4096;
      const char* Br = smem + 8192 + p * 16384;
      f16x8 a[4], b[4];
#pragma unroll
      for (int mi = 0; mi < 4; ++mi) a[mi] = *(const f16x8*)(Ar + aoff[mi]);
#pragma unroll
      for (int ni = 0; ni < 4; ++ni) b[ni] = *(const f16x8*)(Br + boff[ni]);
#pragma unroll
      for (int mi = 0; mi < 4; ++mi)
#pragma unroll
        for (int ni = 0; ni < 4; ++ni)
          acc[mi][ni] = __builtin_amdgcn_mfma_f32_16x16x32_f16(
              a[mi], b[ni], acc[mi][ni], 0, 0, 0);
      __syncthreads();
    }
    // fused epilogue: distances + top-2, reset acc
    const int cb = c * 256 + w * 64;
#pragma unroll
    for (int ni = 0; ni < 4; ++ni) {
      const int col = cb + ni * 16 + l15;
      const float ev = e2f[col];
#pragma unroll
      for (int mi = 0; mi < 4; ++mi)
#pragma unroll
        for (int rg = 0; rg < 4; ++rg) {
          float d = fmaf(-2.0f, acc[mi][ni][rg], ev);
          const int s = mi * 4 + rg;
          bool better = d < m1[s];
          m2[s] = fminf(m2[s], better ? m1[s] : d);
          m1[s] = better ? d : m1[s];
          i1[s] = better ? col : i1[s];
          acc[mi][ni][rg] = 0.0f;
        }
    }
  }
#undef STAGE

  // butterfly merge across the 16 lanes sharing each row-set
#pragma unroll
  for (int s = 0; s < 16; ++s) {
#pragma unroll
    for (int off = 1; off < 16; off <<= 1) {
      float om1 = __shfl_xor(m1[s], off);
      float om2 = __shfl_xor(m2[s], off);
      int oi = __shfl_xor(i1[s], off);
      float nm2 = fminf(fminf(m2[s], om2), fmaxf(m1[s], om1));
      bool take = om1 < m1[s];
      m1[s] = take ? om1 : m1[s];
      i1[s] = take ? oi : i1[s];
      m2[s] = nm2;
    }
  }

  float* sm1 = (float*)smem;  // [4][64]
  float* sm2 = (float*)(smem + 1024);
  int* si1 = (int*)(smem + 2048);
  unsigned* swin = (unsigned*)(smem + 3072);
  __syncthreads();
  if (l15 == 0) {
#pragma unroll
    for (int s = 0; s < 16; ++s) {
      int r = (s >> 2) * 16 + g * 4 + (s & 3);
      sm1[w * 64 + r] = m1[s];
      sm2[w * 64 + r] = m2[s];
      si1[w * 64 + r] = i1[s];
    }
  }
  __syncthreads();
  if (tid < 64) {
    int r = tid;
    float am1 = sm1[r], am2 = sm2[r];
    int ai = si1[r];
#pragma unroll
    for (int ww = 1; ww < 4; ++ww) {
      float om1 = sm1[ww * 64 + r], om2 = sm2[ww * 64 + r];
      int oi = si1[ww * 64 + r];
      float nm2 = fminf(fminf(am2, om2), fmaxf(am1, om1));
      bool take = om1 < am1;
      am1 = take ? om1 : am1;
      ai = take ? oi : ai;
      am2 = nm2;
    }
    swin[r] = (unsigned)ai;
    if (am2 - am1 < TAU1) {
      unsigned p = atomicAdd(cnt1, 1u);
      if (p < LIST_CAP) list1[p] = (unsigned)(rowbase + r);
    }
  }
  __syncthreads();
  {
    int r = tid >> 2, part = tid & 3;
    unsigned wv = swin[r];
    const float4* src = (const float4*)(E + (size_t)wv * 256 + part * 64);
    float4* dst = (float4*)(out + (size_t)(rowbase + r) * 256 + part * 64);
#pragma unroll
    for (int q = 0; q < 16; ++q) dst[q] = src[q];
  }
}

// ---- T2: exact fp64 re-argmin of flagged rows, 4 rows/block ----
__global__ __launch_bounds__(256) void vq_exact(
    const float* __restrict__ x, const float* __restrict__ E,
    const double* __restrict__ e2d, float* __restrict__ out,
    const unsigned* __restrict__ cnt1, const unsigned* __restrict__ list1) {
  __shared__ float xs[4][256];
  __shared__ float es[16][260];  // 16-codeword tile, padded rows
  __shared__ unsigned srow[4];
  unsigned n = *cnt1;
  if (n > LIST_CAP) n = LIST_CAP;
  const int tid = threadIdx.x;
  const int wid = tid >> 6, lane = tid & 63;
  const int vl = lane & 15, kq = lane >> 4;
  for (unsigned g0 = blockIdx.x * 4u; g0 < n; g0 += gridDim.x * 4u) {
    unsigned j = g0 + (unsigned)wid;
    unsigned row = list1[j < n ? j : (n - 1)];
    if (lane == 0) srow[wid] = (j < n) ? row : 0xffffffffu;
    ((float4*)xs[wid])[lane] = ((const float4*)(x + (size_t)row * 256))[lane];
    __syncthreads();
    double best = 1e300;
    int bi = 1 << 30;
#pragma unroll 1
    for (int t = 0; t < 256; ++t) {
      {  // stage 16 codewords (16 KB), coalesced
        int rr = tid >> 4, seg = tid & 15;
        const float4* er =
            (const float4*)(E + ((size_t)t * 16 + rr) * 256 + seg * 16);
        float4 v0 = er[0], v1 = er[1], v2 = er[2], v3 = er[3];
        float4* dst = (float4*)&es[rr][seg * 16];
        dst[0] = v0; dst[1] = v1; dst[2] = v2; dst[3] = v3;
      }
      __syncthreads();
      const float* xr = xs[wid] + kq * 64;
      const float* er = &es[vl][kq * 64];
      double a0 = 0, a1 = 0, a2 = 0, a3 = 0;
#pragma unroll
      for (int k = 0; k < 64; k += 4) {
        a0 += (double)xr[k] * (double)er[k];
        a1 += (double)xr[k + 1] * (double)er[k + 1];
        a2 += (double)xr[k + 2] * (double)er[k + 2];
        a3 += (double)xr[k + 3] * (double)er[k + 3];
      }
      double dot = (a0 + a1) + (a2 + a3);
      dot += __shfl_xor(dot, 16);
      dot += __shfl_xor(dot, 32);
      int v = t * 16 + vl;
      double d = e2d[v] - 2.0 * dot;
      if (d < best || (d == best && v < bi)) { best = d; bi = v; }
      __syncthreads();
    }
#pragma unroll
    for (int off = 1; off < 16; off <<= 1) {
      double ob = __shfl_xor(best, off);
      int oi = __shfl_xor(bi, off);
      if (ob < best || (ob == best && oi < bi)) { best = ob; bi = oi; }
    }
    unsigned orow = srow[wid];
    if (orow != 0xffffffffu) {
      float4 v = ((const float4*)(E + (size_t)bi * 256))[lane];
      ((float4*)(out + (size_t)orow * 256))[lane] = v;
    }
    __syncthreads();  // safety: isolate row-groups completely
  }
}

// ---- insurance: exact fp64 scan of ALL rows (only if ws too small) ----
__global__ void scan_all(const float* __restrict__ x,
                         const float* __restrict__ E, float* out) {
  __shared__ double sd[256];
  __shared__ int si[256];
  for (int row = blockIdx.x; row < 32768; row += gridDim.x) {
    const float* xr = x + (size_t)row * 256;
    double best = 1e300;
    int bi = 1 << 30;
    for (int v = threadIdx.x; v < 4096; v += 256) {
      const float* ev = E + (size_t)v * 256;
      double a0 = 0, a1 = 0, a2 = 0, a3 = 0;
      for (int k = 0; k < 256; k += 4) {
        double d0 = (double)xr[k] - (double)ev[k];
        double d1 = (double)xr[k + 1] - (double)ev[k + 1];
        double d2 = (double)xr[k + 2] - (double)ev[k + 2];
        double d3 = (double)xr[k + 3] - (double)ev[k + 3];
        a0 += d0 * d0; a1 += d1 * d1; a2 += d2 * d2; a3 += d3 * d3;
      }
      double d = (a0 + a1) + (a2 + a3);
      if (d < best || (d == best && v < bi)) { best = d; bi = v; }
    }
    sd[threadIdx.x] = best; si[threadIdx.x] = bi;
    __syncthreads();
    for (int s = 128; s > 0; s >>= 1) {
      if ((int)threadIdx.x < s) {
        double ob = sd[threadIdx.x + s];
        int oi = si[threadIdx.x + s];
        if (ob < sd[threadIdx.x] ||
            (ob == sd[threadIdx.x] && oi < si[threadIdx.x])) {
          sd[threadIdx.x] = ob; si[threadIdx.x] = oi;
        }
      }
      __syncthreads();
    }
    int win = si[0];
    __syncthreads();
    out[(size_t)row * 256 + threadIdx.x] = E[(size_t)win * 256 + threadIdx.x];
  }
}

extern "C" void kernel_launch(void* const* d_in, const int* in_sizes, int n_in,
                              void* d_out, int out_size, void* d_ws,
                              size_t ws_size, hipStream_t stream) {
  (void)in_sizes; (void)n_in; (void)out_size;
  const float* x = (const float*)d_in[0];
  const float* E = (const float*)d_in[1];
  float* out = (float*)d_out;
  char* ws = (char*)d_ws;
  // ws layout: [cnt 64][e2f 16K][e2d 32K][ehi 2M][list1 256K][xpack 32M?]
  const size_t XOFF = 64 + 16384 + 32768 + 2097152 + 262144;  // 2408512
  const size_t NEED_BIG = XOFF + 33554432;
  if (ws_size < XOFF) {
    scan_all<<<2048, 256, 0, stream>>>(x, E, out);
    return;
  }
  unsigned* cnt1 = (unsigned*)ws;
  float* e2f = (float*)(ws + 64);
  double* e2d = (double*)(ws + 64 + 16384);
  char* ehi = ws + 64 + 16384 + 32768;
  unsigned* list1 = (unsigned*)(ehi + 2097152);
  char* xpack = (ws_size >= NEED_BIG) ? (ws + XOFF) : (char*)d_out;

  hipMemsetAsync(ws, 0, 64, stream);
  pack_x<<<2048, 256, 0, stream>>>(x, xpack);
  pack_e<<<256, 256, 0, stream>>>(E, ehi, e2f, e2d);
  vq_main<<<512, 256, 40960, stream>>>(xpack, ehi, e2f, E, out, cnt1, list1);
  vq_exact<<<256, 256, 0, stream>>>(x, E, e2d, out, cnt1, list1);
}